// Round 7
// baseline (188.829 us; speedup 1.0000x reference)
//
#include <hip/hip_runtime.h>

typedef short bf16x8 __attribute__((ext_vector_type(8)));
typedef float f32x4 __attribute__((ext_vector_type(4)));

#define MFMA16(a, b, c) __builtin_amdgcn_mfma_f32_16x16x32_bf16(a, b, c, 0, 0, 0)

__device__ __forceinline__ unsigned short f2bf(float f) {
    unsigned int u = __float_as_uint(f);
    u += 0x7FFFu + ((u >> 16) & 1u);   // round-to-nearest-even
    return (unsigned short)(u >> 16);
}
// packed pair: low16 = bf16(a), high16 = bf16(b)
__device__ __forceinline__ unsigned int f2bf2(float a, float b) {
    unsigned int ua = __float_as_uint(a);
    ua += 0x7FFFu + ((ua >> 16) & 1u);
    unsigned int ub = __float_as_uint(b);
    ub += 0x7FFFu + ((ub >> 16) & 1u);
    return (ua >> 16) | (ub & 0xFFFF0000u);
}
#define DPPADD(v, CTRL)                                                        \
    {                                                                          \
        int _t = __builtin_amdgcn_mov_dpp(__float_as_int(v), CTRL, 0xf, 0xf, true); \
        v += __int_as_float(_t);                                               \
    }

// ---------------- workspace layout (bytes) ----------------
#define WQT_OFF 0        // ushort[576*192]  W_qkv^T bf16, Q rows pre-scaled by scale*log2e
#define WOT_OFF 221184   // ushort[192*192]  W_out^T  bf16
#define BQ_OFF  294912   // float[576]       b_qkv, Q part pre-scaled
#define TBL_OFF 297216   // float[6*4*64*16] bias table [h][mb][lane][f][r], *log2e
// total 395520 bytes

// ================= prep: weight transpose + bias table =================
__global__ void prep_kernel(const float* __restrict__ Wqkv,
                            const float* __restrict__ bqkv,
                            const float* __restrict__ Wout,
                            const float* __restrict__ rel,
                            unsigned short* __restrict__ WqT,
                            unsigned short* __restrict__ WoT,
                            float* __restrict__ bq,
                            float* __restrict__ tblB) {
    __shared__ float tile[32][33];
    const float LOG2E = 1.4426950408889634f;
    const float SCALE = 0.17677669529663687f * 1.4426950408889634f; // 1/sqrt(32)*log2e
    int bid = blockIdx.x;
    int tx = threadIdx.x & 31, ty = threadIdx.x >> 5;
    if (bid < 108) {                       // W_qkv [192][576] -> WqT [576][192]
        int tn = bid % 18, tc = bid / 18;
#pragma unroll
        for (int i = 0; i < 4; ++i)
            tile[ty + i * 8][tx] = Wqkv[(tc * 32 + ty + i * 8) * 576 + tn * 32 + tx];
        __syncthreads();
        bool isQ = (tn < 6);
#pragma unroll
        for (int i = 0; i < 4; ++i) {
            float v = tile[tx][ty + i * 8];
            if (isQ) v *= SCALE;
            WqT[(tn * 32 + ty + i * 8) * 192 + tc * 32 + tx] = f2bf(v);
        }
    } else if (bid < 144) {                // W_out [192][192] -> WoT [192][192]
        int bb = bid - 108;
        int tn = bb % 6, tc = bb / 6;
#pragma unroll
        for (int i = 0; i < 4; ++i)
            tile[ty + i * 8][tx] = Wout[(tc * 32 + ty + i * 8) * 192 + tn * 32 + tx];
        __syncthreads();
#pragma unroll
        for (int i = 0; i < 4; ++i)
            WoT[(tn * 32 + ty + i * 8) * 192 + tc * 32 + tx] = f2bf(tile[tx][ty + i * 8]);
    } else if (bid == 144) {
        for (int i = threadIdx.x; i < 576; i += 256) {
            float v = bqkv[i];
            if (i < 192) v *= SCALE;
            bq[i] = v;
        }
    } else {                               // bias table, bid 145..240
        int e = (bid - 145) * 256 + threadIdx.x;   // e = (((h*4+mb)*64+lane)*16 + f*4 + r
        int r = e & 3, f = (e >> 2) & 3;
        int lane = (e >> 4) & 63, mb = (e >> 10) & 3, h = e >> 12;
        int g = lane >> 4, l15 = lane & 15;
        int qy = l15 >> 2, qx = l15 & 3;
        int dz = mb - f + 3, dy = g - qy + 3, dx = r - qx + 3;
        tblB[e] = rel[((h * 7 + dz) * 7 + dy) * 7 + dx] * LOG2E;
    }
}

// ---------------- LDS layout (ushort units) ----------------
// sX  frag-linear [kk][g][tb][l15][8] (12288 us); aliased by per-wave P in phase 2
// sQK [64][392]: Q cols 0..191 | K cols 192..383
// sVt [192][72]  V transposed [c][t]
// sO  [64][200]  attention output row-major [t][c]
#define OFF_X   0
#define OFF_QK  12288
#define OFF_VT  37376
#define OFF_O   51200
#define SMEM_US 64000      // 128000 bytes

__global__ __launch_bounds__(512, 2) void wmsa_kernel(
    const float* __restrict__ x, const float* __restrict__ tblB,
    const float* __restrict__ bout,
    const unsigned short* __restrict__ WqT,
    const unsigned short* __restrict__ WoT,
    const float* __restrict__ bq, float* __restrict__ out) {
    __shared__ __align__(16) unsigned short smem[SMEM_US];

    const int tid = threadIdx.x;
    const int bw = blockIdx.x;
    const int b  = bw >> 9;
    const int w  = bw & 511;
    const int wz = w >> 6, wy = (w >> 3) & 7, wx = w & 7;

    const int lane = tid & 63;
    const int wv   = tid >> 6;     // wave id 0..7
    const int g    = lane >> 4;    // quad id 0..3
    const int l15  = lane & 15;

    // ---------- phase 0: x window fp32 -> bf16 LDS, frag-linear, roll(-2) folded ----------
    {
        int t = tid >> 3, q8 = tid & 7;           // 8 threads per token
        int tz = t >> 4, ty = (t >> 2) & 3, tx = t & 3;
        int gz = (wz * 4 + tz + 2) & 31;
        int gy = (wy * 4 + ty + 2) & 31;
        int gx = (wx * 4 + tx + 2) & 31;
        const float* xp = x + ((((b * 32 + gz) * 32 + gy) * 32 + gx)) * 192;
        int g0 = q8 >> 1, j0 = (q8 & 1) * 4, lt = t & 15;
#pragma unroll
        for (int k = 0; k < 6; ++k) {
            float4 v = *(const float4*)(xp + q8 * 4 + k * 32);
            uint2 pk;
            pk.x = f2bf2(v.x, v.y);
            pk.y = f2bf2(v.z, v.w);
            *(uint2*)&smem[OFF_X + ((((k * 4 + g0) * 4 + tz) * 16 + lt) * 8) + j0] = pk;
        }
    }

    // hoist first phase-1 W fragment (global, overlaps barrier drain)
    int nb = wv;
    bf16x8 wfr[6];
    {
        const unsigned short* wp = WqT + (nb * 16 + l15) * 192 + g * 8;
#pragma unroll
        for (int kk = 0; kk < 6; ++kk) wfr[kk] = *(const bf16x8*)(wp + kk * 32);
    }
    __syncthreads();

    // ---------- phase 1: QKV (operand-swapped for Q/K -> b64 LDS writes) ----------
    {
        bf16x8 xfr[4][6];          // all 24 X fragments register-resident
#pragma unroll
        for (int tb = 0; tb < 4; ++tb)
#pragma unroll
            for (int kk = 0; kk < 6; ++kk)
                xfr[tb][kk] = *(const bf16x8*)&smem[OFF_X + (((kk * 4 + g) * 4 + tb) * 16 + l15) * 8];

        while (true) {
            int nbN = nb + 8;
            bool more = (nbN < 36);
            bf16x8 wfrN[6];
            if (more) {
                const unsigned short* wp = WqT + (nbN * 16 + l15) * 192 + g * 8;
#pragma unroll
                for (int kk = 0; kk < 6; ++kk) wfrN[kk] = *(const bf16x8*)(wp + kk * 32);
            }
            if (nb < 24) {                 // Q/K: C = W·X -> regs = channels (b64 writes)
                f32x4 bqv = *(const f32x4*)(bq + nb * 16 + g * 4);
                int qkcol = (nb < 12) ? nb * 16 : 192 + (nb - 12) * 16;
#pragma unroll
                for (int tb = 0; tb < 4; ++tb) {
                    f32x4 acc = bqv;
#pragma unroll
                    for (int kk = 0; kk < 6; ++kk) acc = MFMA16(wfr[kk], xfr[tb][kk], acc);
                    uint2 pk;
                    pk.x = f2bf2(acc[0], acc[1]);
                    pk.y = f2bf2(acc[2], acc[3]);
                    *(uint2*)&smem[OFF_QK + (tb * 16 + l15) * 392 + qkcol + g * 4] = pk;
                }
            } else {                       // V: C = X·W -> regs = tokens, Vt[c][t] b64
                float bs = bq[nb * 16 + l15];
                int c = (nb - 24) * 16 + l15;
#pragma unroll
                for (int tb = 0; tb < 4; ++tb) {
                    f32x4 acc = {bs, bs, bs, bs};
#pragma unroll
                    for (int kk = 0; kk < 6; ++kk) acc = MFMA16(xfr[tb][kk], wfr[kk], acc);
                    uint2 pk;
                    pk.x = f2bf2(acc[0], acc[1]);
                    pk.y = f2bf2(acc[2], acc[3]);
                    *(uint2*)&smem[OFF_VT + c * 72 + tb * 16 + g * 4] = pk;
                }
            }
            if (!more) break;
            nb = nbN;
#pragma unroll
            for (int kk = 0; kk < 6; ++kk) wfr[kk] = wfrN[kk];
        }
    }
    __syncthreads();

    // ---------- phase 2: attention, 3 iterations per wave ----------
    const bool sz = (wz == 7), sy = (wy == 7), sx = (wx == 7);
    {
        const int qy = l15 >> 2, qx = l15 & 3;
        const bool my = sy && ((g < 2) != (qy < 2));
        bool mxr[4];
#pragma unroll
        for (int r = 0; r < 4; ++r) mxr[r] = sx && ((r < 2) != (qx < 2));
        unsigned short* pb = &smem[OFF_X + wv * 1152];   // aliases dead sX
        for (int it = wv * 3; it < wv * 3 + 3; ++it) {
            int h = it >> 2, mb = it & 3;
            bf16x8 qf = *(const bf16x8*)&smem[OFF_QK + (mb * 16 + l15) * 392 + h * 32 + g * 8];
            f32x4 s[4];
#pragma unroll
            for (int f = 0; f < 4; ++f) {
                bf16x8 kf = *(const bf16x8*)&smem[OFF_QK + (f * 16 + l15) * 392 + 192 + h * 32 + g * 8];
                f32x4 z = {0.f, 0.f, 0.f, 0.f};
                s[f] = MFMA16(qf, kf, z);
            }
            // bias (precomputed global table, coalesced) + mask + exp2
            const f32x4* tp = (const f32x4*)(tblB + ((h * 4 + mb) * 64 + lane) * 16);
#pragma unroll
            for (int f = 0; f < 4; ++f) {
                f32x4 bv = tp[f];
                bool mzy = (sz && ((mb < 2) != (f < 2))) | my;
#pragma unroll
                for (int r = 0; r < 4; ++r) {
                    float v = s[f][r] + bv[r];
                    v = (mzy | mxr[r]) ? -1e30f : v;
                    s[f][r] = exp2f(v);
                }
            }
            // row sums via DPP, normalize P
            float inv[4];
#pragma unroll
            for (int r = 0; r < 4; ++r) {
                float sm = (s[0][r] + s[1][r]) + (s[2][r] + s[3][r]);
                DPPADD(sm, 0xB1);    // quad_perm [1,0,3,2]
                DPPADD(sm, 0x4E);    // quad_perm [2,3,0,1]
                DPPADD(sm, 0x124);   // row_ror:4
                DPPADD(sm, 0x128);   // row_ror:8
                inv[r] = __builtin_amdgcn_rcpf(sm);
            }
            // P (normalized) -> per-wave LDS -> A/B frags
#pragma unroll
            for (int f = 0; f < 4; ++f) {
                unsigned int u01 = f2bf2(s[f][0] * inv[0], s[f][1] * inv[1]);
                unsigned int u23 = f2bf2(s[f][2] * inv[2], s[f][3] * inv[3]);
                unsigned short* pw = &pb[(g * 4) * 72 + f * 16 + l15];
                pw[0]   = (unsigned short)u01;
                pw[72]  = (unsigned short)(u01 >> 16);
                pw[144] = (unsigned short)u23;
                pw[216] = (unsigned short)(u23 >> 16);
            }
            // PV operand-swapped: O^T = V·P^T -> regs = channels -> b64 writes
            f32x4 o0 = {0.f, 0.f, 0.f, 0.f}, o1 = {0.f, 0.f, 0.f, 0.f};
#pragma unroll
            for (int kt = 0; kt < 2; ++kt) {
                bf16x8 pf = *(const bf16x8*)&pb[l15 * 72 + kt * 32 + g * 8];
                bf16x8 v0 = *(const bf16x8*)&smem[OFF_VT + (h * 32 + l15) * 72 + kt * 32 + g * 8];
                bf16x8 v1 = *(const bf16x8*)&smem[OFF_VT + (h * 32 + 16 + l15) * 72 + kt * 32 + g * 8];
                o0 = MFMA16(v0, pf, o0);
                o1 = MFMA16(v1, pf, o1);
            }
            uint2 p0, p1;
            p0.x = f2bf2(o0[0], o0[1]); p0.y = f2bf2(o0[2], o0[3]);
            p1.x = f2bf2(o1[0], o1[1]); p1.y = f2bf2(o1[2], o1[3]);
            int oi = OFF_O + (mb * 16 + l15) * 200 + h * 32 + g * 4;
            *(uint2*)&smem[oi]      = p0;
            *(uint2*)&smem[oi + 16] = p1;
        }
    }

    // hoist first phase-3 W fragments (global, overlaps barrier drain)
    const int tb3 = wv >> 1, nb0 = (wv & 1) * 6;
    bf16x8 w3[6];
    {
        const unsigned short* wp = WoT + (nb0 * 16 + l15) * 192 + g * 8;
#pragma unroll
        for (int kk = 0; kk < 6; ++kk) w3[kk] = *(const bf16x8*)(wp + kk * 32);
    }
    __syncthreads();

    // ---------- phase 3: out^T = Wo·O -> regs = channels -> dwordx4 global stores ----------
    {
        bf16x8 ofr[6];
#pragma unroll
        for (int kk = 0; kk < 6; ++kk)
            ofr[kk] = *(const bf16x8*)&smem[OFF_O + (tb3 * 16 + l15) * 200 + kk * 32 + g * 8];
        const int gz = (wz * 4 + tb3 + 2) & 31;   // roll(+2) folded in
        const int gy = (wy * 4 + (l15 >> 2) + 2) & 31;
        const int gx = (wx * 4 + (l15 & 3) + 2) & 31;
        float* op = out + ((((b * 32 + gz) * 32 + gy) * 32 + gx)) * 192;
#pragma unroll
        for (int u = 0; u < 6; ++u) {
            int nb3 = nb0 + u;
            bf16x8 wf[6];
            if (u == 0) {
#pragma unroll
                for (int kk = 0; kk < 6; ++kk) wf[kk] = w3[kk];
            } else {
                const unsigned short* wp = WoT + (nb3 * 16 + l15) * 192 + g * 8;
#pragma unroll
                for (int kk = 0; kk < 6; ++kk) wf[kk] = *(const bf16x8*)(wp + kk * 32);
            }
            f32x4 acc = *(const f32x4*)(bout + nb3 * 16 + g * 4);
#pragma unroll
            for (int kk = 0; kk < 6; ++kk) acc = MFMA16(wf[kk], ofr[kk], acc);
            *(f32x4*)(op + nb3 * 16 + g * 4) = acc;
        }
    }
}

extern "C" void kernel_launch(void* const* d_in, const int* in_sizes, int n_in,
                              void* d_out, int out_size, void* d_ws, size_t ws_size,
                              hipStream_t stream) {
    const float* x    = (const float*)d_in[0];
    const float* Wqkv = (const float*)d_in[1];
    const float* bqkv = (const float*)d_in[2];
    const float* rel  = (const float*)d_in[3];
    const float* Wout = (const float*)d_in[4];
    const float* bout = (const float*)d_in[5];

    unsigned short* WqT = (unsigned short*)((char*)d_ws + WQT_OFF);
    unsigned short* WoT = (unsigned short*)((char*)d_ws + WOT_OFF);
    float*          bq  = (float*)((char*)d_ws + BQ_OFF);
    float*          tbl = (float*)((char*)d_ws + TBL_OFF);
    float*          out = (float*)d_out;

    prep_kernel<<<241, 256, 0, stream>>>(Wqkv, bqkv, Wout, rel, WqT, WoT, bq, tbl);
    wmsa_kernel<<<1024, 512, 0, stream>>>(x, tbl, bout, WqT, WoT, bq, out);
}

// Round 8
// 163.651 us; speedup vs baseline: 1.1538x; 1.1538x over previous
//
#include <hip/hip_runtime.h>

typedef short bf16x8 __attribute__((ext_vector_type(8)));
typedef float f32x4 __attribute__((ext_vector_type(4)));

#define MFMA16(a, b, c) __builtin_amdgcn_mfma_f32_16x16x32_bf16(a, b, c, 0, 0, 0)

__device__ __forceinline__ unsigned short f2bf(float f) {
    unsigned int u = __float_as_uint(f);
    u += 0x7FFFu + ((u >> 16) & 1u);   // round-to-nearest-even
    return (unsigned short)(u >> 16);
}
// packed pair: low16 = bf16(a), high16 = bf16(b)
__device__ __forceinline__ unsigned int f2bf2(float a, float b) {
    unsigned int ua = __float_as_uint(a);
    ua += 0x7FFFu + ((ua >> 16) & 1u);
    unsigned int ub = __float_as_uint(b);
    ub += 0x7FFFu + ((ub >> 16) & 1u);
    return (ua >> 16) | (ub & 0xFFFF0000u);
}
#define DPPADD(v, CTRL)                                                        \
    {                                                                          \
        int _t = __builtin_amdgcn_mov_dpp(__float_as_int(v), CTRL, 0xf, 0xf, true); \
        v += __int_as_float(_t);                                               \
    }

// ---------------- workspace layout (bytes) ----------------
#define WQT_OFF 0        // ushort[576*192]  W_qkv^T bf16, Q rows pre-scaled by scale*log2e
#define WOT_OFF 221184   // ushort[192*192]  W_out^T  bf16
#define BQ_OFF  294912   // float[576]       b_qkv, Q part pre-scaled
#define TBL_OFF 297216   // float[6*4*64*16] bias table [h][mb][lane][f][r], *log2e
// total 395520 bytes

// ================= prep: weight transpose + bias table =================
__global__ void prep_kernel(const float* __restrict__ Wqkv,
                            const float* __restrict__ bqkv,
                            const float* __restrict__ Wout,
                            const float* __restrict__ rel,
                            unsigned short* __restrict__ WqT,
                            unsigned short* __restrict__ WoT,
                            float* __restrict__ bq,
                            float* __restrict__ tblB) {
    __shared__ float tile[32][33];
    const float LOG2E = 1.4426950408889634f;
    const float SCALE = 0.17677669529663687f * 1.4426950408889634f; // 1/sqrt(32)*log2e
    int bid = blockIdx.x;
    int tx = threadIdx.x & 31, ty = threadIdx.x >> 5;
    if (bid < 108) {                       // W_qkv [192][576] -> WqT [576][192]
        int tn = bid % 18, tc = bid / 18;
#pragma unroll
        for (int i = 0; i < 4; ++i)
            tile[ty + i * 8][tx] = Wqkv[(tc * 32 + ty + i * 8) * 576 + tn * 32 + tx];
        __syncthreads();
        bool isQ = (tn < 6);
#pragma unroll
        for (int i = 0; i < 4; ++i) {
            float v = tile[tx][ty + i * 8];
            if (isQ) v *= SCALE;
            WqT[(tn * 32 + ty + i * 8) * 192 + tc * 32 + tx] = f2bf(v);
        }
    } else if (bid < 144) {                // W_out [192][192] -> WoT [192][192]
        int bb = bid - 108;
        int tn = bb % 6, tc = bb / 6;
#pragma unroll
        for (int i = 0; i < 4; ++i)
            tile[ty + i * 8][tx] = Wout[(tc * 32 + ty + i * 8) * 192 + tn * 32 + tx];
        __syncthreads();
#pragma unroll
        for (int i = 0; i < 4; ++i)
            WoT[(tn * 32 + ty + i * 8) * 192 + tc * 32 + tx] = f2bf(tile[tx][ty + i * 8]);
    } else if (bid == 144) {
        for (int i = threadIdx.x; i < 576; i += 256) {
            float v = bqkv[i];
            if (i < 192) v *= SCALE;
            bq[i] = v;
        }
    } else {                               // bias table, bid 145..240
        int e = (bid - 145) * 256 + threadIdx.x;   // e = (((h*4+mb)*64+lane)*16 + f*4 + r
        int r = e & 3, f = (e >> 2) & 3;
        int lane = (e >> 4) & 63, mb = (e >> 10) & 3, h = e >> 12;
        int g = lane >> 4, l15 = lane & 15;
        int qy = l15 >> 2, qx = l15 & 3;
        int dz = mb - f + 3, dy = g - qy + 3, dx = r - qx + 3;
        tblB[e] = rel[((h * 7 + dz) * 7 + dy) * 7 + dx] * LOG2E;
    }
}

// ---------------- LDS layout (ushort units) ----------------
// sX  frag-linear [kk][g][m][l15][8] (12288 us); aliased by per-wave P in phase 2
// sQK [64][392] bf16 Q(cols 0..191, pre-scaled) | K(192..383)
// sVt [192][72] bf16 V transposed [c][t]
// sO  [64][208] bf16 attention output [t][c]
#define OFF_X   0
#define OFF_P   0          // per-wave [16][72], aliases sX (dead after phase 1)
#define OFF_QK  12288
#define OFF_VT  37376
#define OFF_O   51200
#define SMEM_US 64512      // 129024 bytes

__global__ __launch_bounds__(512) void wmsa_kernel(
    const float* __restrict__ x, const float* __restrict__ tblB,
    const float* __restrict__ bout,
    const unsigned short* __restrict__ WqT,
    const unsigned short* __restrict__ WoT,
    const float* __restrict__ bq, float* __restrict__ out) {
    __shared__ __align__(16) unsigned short smem[SMEM_US];

    const int tid = threadIdx.x;
    const int bw = blockIdx.x;
    const int b  = bw >> 9;
    const int w  = bw & 511;
    const int wz = w >> 6, wy = (w >> 3) & 7, wx = w & 7;

    const int lane = tid & 63;
    const int wv   = tid >> 6;     // wave id 0..7
    const int g    = lane >> 4;    // quad id 0..3
    const int l15  = lane & 15;

    // ---------- phase 0: x window fp32 -> bf16 LDS, frag-linear, roll(-2) folded ----------
    {
        int t = tid >> 3, q8 = tid & 7;           // 8 threads per token
        int tz = t >> 4, ty = (t >> 2) & 3, tx = t & 3;
        int gz = (wz * 4 + tz + 2) & 31;
        int gy = (wy * 4 + ty + 2) & 31;
        int gx = (wx * 4 + tx + 2) & 31;
        const float* xp = x + ((((b * 32 + gz) * 32 + gy) * 32 + gx)) * 192;
        int g0 = q8 >> 1, j0 = (q8 & 1) * 4, lt = t & 15;
#pragma unroll
        for (int k = 0; k < 6; ++k) {
            float4 v = *(const float4*)(xp + q8 * 4 + k * 32);
            uint2 pk;
            pk.x = f2bf2(v.x, v.y);
            pk.y = f2bf2(v.z, v.w);
            *(uint2*)&smem[OFF_X + ((((k * 4 + g0) * 4 + tz) * 16 + lt) * 8) + j0] = pk;
        }
    }

    // hoist first phase-1 B fragment (global only, overlaps barrier drain)
    int nb = wv;
    float bias = bq[nb * 16 + l15];
    bf16x8 bfr[6];
    {
        const unsigned short* wp = WqT + (nb * 16 + l15) * 192 + g * 8;
#pragma unroll
        for (int kk = 0; kk < 6; ++kk) bfr[kk] = *(const bf16x8*)(wp + kk * 32);
    }
    __syncthreads();

    // ---------- phase 1: QKV = Xw(64x192) @ WqT^T + bq  (64x576) ----------
    {
        bf16x8 afr[4][6];          // A fragments cached: 4 m-blocks x 6 k-iters
#pragma unroll
        for (int m = 0; m < 4; ++m)
#pragma unroll
            for (int kk = 0; kk < 6; ++kk)
                afr[m][kk] = *(const bf16x8*)&smem[OFF_X + (((kk * 4 + g) * 4 + m) * 16 + l15) * 8];

        while (true) {
            int nbN = nb + 8;
            bool more = (nbN < 36);
            bf16x8 bfrN[6];
            float biasN = 0.f;
            if (more) {
                biasN = bq[nbN * 16 + l15];
                const unsigned short* wp = WqT + (nbN * 16 + l15) * 192 + g * 8;
#pragma unroll
                for (int kk = 0; kk < 6; ++kk) bfrN[kk] = *(const bf16x8*)(wp + kk * 32);
            }
            int colg = nb * 16 + l15;
            bool isV = (nb >= 24);
#pragma unroll
            for (int m = 0; m < 4; ++m) {
                f32x4 acc = {bias, bias, bias, bias};
#pragma unroll
                for (int kk = 0; kk < 6; ++kk) acc = MFMA16(afr[m][kk], bfr[kk], acc);
                int row0 = m * 16 + g * 4;
                unsigned int u01 = f2bf2(acc[0], acc[1]);
                unsigned int u23 = f2bf2(acc[2], acc[3]);
                if (!isV) {                       // Q/K -> sQK[t][col]
                    unsigned short* qk = &smem[OFF_QK + row0 * 392 + colg];
                    qk[0]    = (unsigned short)u01;
                    qk[392]  = (unsigned short)(u01 >> 16);
                    qk[784]  = (unsigned short)u23;
                    qk[1176] = (unsigned short)(u23 >> 16);
                } else {                          // V -> sVt[c][t], 4 contiguous t
                    uint2 pk; pk.x = u01; pk.y = u23;
                    *(uint2*)&smem[OFF_VT + (colg - 384) * 72 + row0] = pk;
                }
            }
            if (!more) break;
            nb = nbN;
            bias = biasN;
#pragma unroll
            for (int kk = 0; kk < 6; ++kk) bfr[kk] = bfrN[kk];
        }
    }
    __syncthreads();

    // ---------- phase 2: per (head, 16-row block) attention ----------
    const bool sz = (wz == 7), sy = (wy == 7), sx = (wx == 7);
    {
        const int qy = l15 >> 2, qx = l15 & 3;
        const bool my = sy && ((g < 2) != (qy < 2));
        bool mxr[4];
#pragma unroll
        for (int r = 0; r < 4; ++r) mxr[r] = sx && ((r < 2) != (qx < 2));
        unsigned short* pb = &smem[OFF_P + wv * 1152];
        for (int it = wv * 3; it < wv * 3 + 3; ++it) {
            int h = it >> 2, mb = it & 3;
            // bias table loads first: independent VMEM, overlaps the LDS+MFMA below
            const f32x4* tp = (const f32x4*)(tblB + ((h * 4 + mb) * 64 + lane) * 16);
            f32x4 bv[4];
#pragma unroll
            for (int f = 0; f < 4; ++f) bv[f] = tp[f];
            bf16x8 qf = *(const bf16x8*)&smem[OFF_QK + (mb * 16 + l15) * 392 + h * 32 + g * 8];
            f32x4 s[4];
#pragma unroll
            for (int f = 0; f < 4; ++f) {
                bf16x8 kf = *(const bf16x8*)&smem[OFF_QK + (f * 16 + l15) * 392 + 192 + h * 32 + g * 8];
                f32x4 z = {0.f, 0.f, 0.f, 0.f};
                s[f] = MFMA16(qf, kf, z);
            }
            // bias + shift mask + exp2 (log2 domain; masked -> exp2(-1e30)=0)
#pragma unroll
            for (int f = 0; f < 4; ++f) {
                bool mzy = (sz && ((mb < 2) != (f < 2))) | my;
#pragma unroll
                for (int r = 0; r < 4; ++r) {
                    float v = s[f][r] + bv[f][r];
                    v = (mzy | mxr[r]) ? -1e30f : v;
                    s[f][r] = exp2f(v);
                }
            }
            // row sums via DPP; P stays unnormalized
            float inv[4];
#pragma unroll
            for (int r = 0; r < 4; ++r) {
                float sm = (s[0][r] + s[1][r]) + (s[2][r] + s[3][r]);
                DPPADD(sm, 0xB1);    // quad_perm [1,0,3,2]
                DPPADD(sm, 0x4E);    // quad_perm [2,3,0,1]
                DPPADD(sm, 0x124);   // row_ror:4
                DPPADD(sm, 0x128);   // row_ror:8
                inv[r] = __builtin_amdgcn_rcpf(sm);
            }
            // P (C-layout) -> per-wave LDS -> A-frags (same wave, no barrier)
#pragma unroll
            for (int f = 0; f < 4; ++f) {
                unsigned int u01 = f2bf2(s[f][0], s[f][1]);
                unsigned int u23 = f2bf2(s[f][2], s[f][3]);
                unsigned short* pw = &pb[(g * 4) * 72 + f * 16 + l15];
                pw[0]   = (unsigned short)u01;
                pw[72]  = (unsigned short)(u01 >> 16);
                pw[144] = (unsigned short)u23;
                pw[216] = (unsigned short)(u23 >> 16);
            }
            // PV: O(16x32) = P(16x64) @ V(64x32), then normalize by inv[r]
            f32x4 o0 = {0.f, 0.f, 0.f, 0.f}, o1 = {0.f, 0.f, 0.f, 0.f};
#pragma unroll
            for (int kt = 0; kt < 2; ++kt) {
                bf16x8 pf = *(const bf16x8*)&pb[l15 * 72 + kt * 32 + g * 8];
                bf16x8 v0 = *(const bf16x8*)&smem[OFF_VT + (h * 32 + l15) * 72 + kt * 32 + g * 8];
                bf16x8 v1 = *(const bf16x8*)&smem[OFF_VT + (h * 32 + 16 + l15) * 72 + kt * 32 + g * 8];
                o0 = MFMA16(pf, v0, o0);
                o1 = MFMA16(pf, v1, o1);
            }
#pragma unroll
            for (int r = 0; r < 4; ++r) { o0[r] *= inv[r]; o1[r] *= inv[r]; }
            unsigned int a0 = f2bf2(o0[0], o0[1]), a1 = f2bf2(o0[2], o0[3]);
            unsigned int c0 = f2bf2(o1[0], o1[1]), c1 = f2bf2(o1[2], o1[3]);
            unsigned short* ow = &smem[OFF_O + (mb * 16 + g * 4) * 208 + h * 32 + l15];
            ow[0]        = (unsigned short)a0;
            ow[208]      = (unsigned short)(a0 >> 16);
            ow[416]      = (unsigned short)a1;
            ow[624]      = (unsigned short)(a1 >> 16);
            ow[16]       = (unsigned short)c0;
            ow[16 + 208] = (unsigned short)(c0 >> 16);
            ow[16 + 416] = (unsigned short)c1;
            ow[16 + 624] = (unsigned short)(c1 >> 16);
        }
    }

    // hoist first phase-3 B fragment + bias (global only, overlaps barrier drain)
    const int mw = wv >> 2, nq = wv & 3;
    int col0 = nq * 16 + l15;
    float boc = bout[col0];
    bf16x8 bfr3[6];
    {
        const unsigned short* wp = WoT + col0 * 192 + g * 8;
#pragma unroll
        for (int kk = 0; kk < 6; ++kk) bfr3[kk] = *(const bf16x8*)(wp + kk * 32);
    }
    __syncthreads();

    // ---------- phase 3: out = O(64x192) @ WoT^T + b_out, scatter to global ----------
    {
        bf16x8 ofr[2][6];
#pragma unroll
        for (int mi = 0; mi < 2; ++mi)
#pragma unroll
            for (int kk = 0; kk < 6; ++kk)
                ofr[mi][kk] = *(const bf16x8*)&smem[OFF_O + ((mw * 2 + mi) * 16 + l15) * 208 + kk * 32 + g * 8];
#pragma unroll
        for (int nbi = 0; nbi < 3; ++nbi) {
            int col = (nq + nbi * 4) * 16 + l15;
            // prefetch next n-block's W fragments before computing this one
            float boN = 0.f;
            bf16x8 bfrN[6];
            if (nbi < 2) {
                int colN = (nq + (nbi + 1) * 4) * 16 + l15;
                boN = bout[colN];
                const unsigned short* wp = WoT + colN * 192 + g * 8;
#pragma unroll
                for (int kk = 0; kk < 6; ++kk) bfrN[kk] = *(const bf16x8*)(wp + kk * 32);
            }
#pragma unroll
            for (int mi = 0; mi < 2; ++mi) {
                f32x4 acc = {boc, boc, boc, boc};
#pragma unroll
                for (int kk = 0; kk < 6; ++kk) acc = MFMA16(ofr[mi][kk], bfr3[kk], acc);
                int m = mw * 2 + mi;                    // token t = m*16 + g*4 + r
                int gz = (wz * 4 + m + 2) & 31;         // roll(+2) folded in
                int gy = (wy * 4 + g + 2) & 31;
#pragma unroll
                for (int r = 0; r < 4; ++r) {
                    int gx = (wx * 4 + r + 2) & 31;
                    out[(((b * 32 + gz) * 32 + gy) * 32 + gx) * 192 + col] = acc[r];
                }
            }
            boc = boN;
#pragma unroll
            for (int kk = 0; kk < 6; ++kk) bfr3[kk] = bfrN[kk];
        }
    }
}

extern "C" void kernel_launch(void* const* d_in, const int* in_sizes, int n_in,
                              void* d_out, int out_size, void* d_ws, size_t ws_size,
                              hipStream_t stream) {
    const float* x    = (const float*)d_in[0];
    const float* Wqkv = (const float*)d_in[1];
    const float* bqkv = (const float*)d_in[2];
    const float* rel  = (const float*)d_in[3];
    const float* Wout = (const float*)d_in[4];
    const float* bout = (const float*)d_in[5];

    unsigned short* WqT = (unsigned short*)((char*)d_ws + WQT_OFF);
    unsigned short* WoT = (unsigned short*)((char*)d_ws + WOT_OFF);
    float*          bq  = (float*)((char*)d_ws + BQ_OFF);
    float*          tbl = (float*)((char*)d_ws + TBL_OFF);
    float*          out = (float*)d_out;

    prep_kernel<<<241, 256, 0, stream>>>(Wqkv, bqkv, Wout, rel, WqT, WoT, bq, tbl);
    wmsa_kernel<<<1024, 512, 0, stream>>>(x, tbl, bout, WqT, WoT, bq, out);
}

// Round 9
// 161.285 us; speedup vs baseline: 1.1708x; 1.0147x over previous
//
#include <hip/hip_runtime.h>

typedef short bf16x8 __attribute__((ext_vector_type(8)));
typedef float f32x4 __attribute__((ext_vector_type(4)));

#define MFMA16(a, b, c) __builtin_amdgcn_mfma_f32_16x16x32_bf16(a, b, c, 0, 0, 0)

__device__ __forceinline__ unsigned short f2bf(float f) {
    unsigned int u = __float_as_uint(f);
    u += 0x7FFFu + ((u >> 16) & 1u);   // round-to-nearest-even
    return (unsigned short)(u >> 16);
}
// packed pair: low16 = bf16(a), high16 = bf16(b)
__device__ __forceinline__ unsigned int f2bf2(float a, float b) {
    unsigned int ua = __float_as_uint(a);
    ua += 0x7FFFu + ((ua >> 16) & 1u);
    unsigned int ub = __float_as_uint(b);
    ub += 0x7FFFu + ((ub >> 16) & 1u);
    return (ua >> 16) | (ub & 0xFFFF0000u);
}
#define DPPADD(v, CTRL)                                                        \
    {                                                                          \
        int _t = __builtin_amdgcn_mov_dpp(__float_as_int(v), CTRL, 0xf, 0xf, true); \
        v += __int_as_float(_t);                                               \
    }

// ---------------- workspace layout (bytes) ----------------
#define WQT_OFF 0        // ushort[576*192]  W_qkv^T bf16, Q rows pre-scaled by scale*log2e
#define WOT_OFF 221184   // ushort[192*192]  W_out^T  bf16
#define BQ_OFF  294912   // float[576]       b_qkv, Q part pre-scaled
#define TBL_OFF 297216   // float[6*4*64*16] bias table [h][mb][lane][f][r], *log2e
// total 395520 bytes

// ================= prep: weight transpose + bias table =================
__global__ void prep_kernel(const float* __restrict__ Wqkv,
                            const float* __restrict__ bqkv,
                            const float* __restrict__ Wout,
                            const float* __restrict__ rel,
                            unsigned short* __restrict__ WqT,
                            unsigned short* __restrict__ WoT,
                            float* __restrict__ bq,
                            float* __restrict__ tblB) {
    __shared__ float tile[32][33];
    const float LOG2E = 1.4426950408889634f;
    const float SCALE = 0.17677669529663687f * 1.4426950408889634f; // 1/sqrt(32)*log2e
    int bid = blockIdx.x;
    int tx = threadIdx.x & 31, ty = threadIdx.x >> 5;
    if (bid < 108) {                       // W_qkv [192][576] -> WqT [576][192]
        int tn = bid % 18, tc = bid / 18;
#pragma unroll
        for (int i = 0; i < 4; ++i)
            tile[ty + i * 8][tx] = Wqkv[(tc * 32 + ty + i * 8) * 576 + tn * 32 + tx];
        __syncthreads();
        bool isQ = (tn < 6);
#pragma unroll
        for (int i = 0; i < 4; ++i) {
            float v = tile[tx][ty + i * 8];
            if (isQ) v *= SCALE;
            WqT[(tn * 32 + ty + i * 8) * 192 + tc * 32 + tx] = f2bf(v);
        }
    } else if (bid < 144) {                // W_out [192][192] -> WoT [192][192]
        int bb = bid - 108;
        int tn = bb % 6, tc = bb / 6;
#pragma unroll
        for (int i = 0; i < 4; ++i)
            tile[ty + i * 8][tx] = Wout[(tc * 32 + ty + i * 8) * 192 + tn * 32 + tx];
        __syncthreads();
#pragma unroll
        for (int i = 0; i < 4; ++i)
            WoT[(tn * 32 + ty + i * 8) * 192 + tc * 32 + tx] = f2bf(tile[tx][ty + i * 8]);
    } else if (bid == 144) {
        for (int i = threadIdx.x; i < 576; i += 256) {
            float v = bqkv[i];
            if (i < 192) v *= SCALE;
            bq[i] = v;
        }
    } else {                               // bias table, bid 145..240
        int e = (bid - 145) * 256 + threadIdx.x;   // e = (((h*4+mb)*64+lane)*16 + f*4 + r
        int r = e & 3, f = (e >> 2) & 3;
        int lane = (e >> 4) & 63, mb = (e >> 10) & 3, h = e >> 12;
        int g = lane >> 4, l15 = lane & 15;
        int qy = l15 >> 2, qx = l15 & 3;
        int dz = mb - f + 3, dy = g - qy + 3, dx = r - qx + 3;
        tblB[e] = rel[((h * 7 + dz) * 7 + dy) * 7 + dx] * LOG2E;
    }
}

// ---------------- LDS layout (ushort units) ----------------
// sX  frag-linear [kk][g][m][l15][8] (12288 us); aliased by per-wave P in phase 2
// sQK [64][392] bf16 Q(cols 0..191, pre-scaled) | K(192..383)
// sVt [192][72] bf16 V transposed [c][t]
// sO  [64][208] bf16 attention output [t][c]
#define OFF_X   0
#define OFF_P   0          // per-wave [16][72], aliases sX (dead after phase 1)
#define OFF_QK  12288
#define OFF_VT  37376
#define OFF_O   51200
#define SMEM_US 64512      // 129024 bytes

__global__ __launch_bounds__(512) void wmsa_kernel(
    const float* __restrict__ x, const float* __restrict__ tblB,
    const float* __restrict__ bout,
    const unsigned short* __restrict__ WqT,
    const unsigned short* __restrict__ WoT,
    const float* __restrict__ bq, float* __restrict__ out) {
    __shared__ __align__(16) unsigned short smem[SMEM_US];

    const int tid = threadIdx.x;
    const int bw = blockIdx.x;
    const int b  = bw >> 9;
    const int w  = bw & 511;
    const int wz = w >> 6, wy = (w >> 3) & 7, wx = w & 7;

    const int lane = tid & 63;
    const int wv   = tid >> 6;     // wave id 0..7
    const int g    = lane >> 4;    // quad id 0..3
    const int l15  = lane & 15;

    // ---------- phase 0: x window fp32 -> bf16 LDS, frag-linear, roll(-2) folded ----------
    {
        int t = tid >> 3, q8 = tid & 7;           // 8 threads per token
        int tz = t >> 4, ty = (t >> 2) & 3, tx = t & 3;
        int gz = (wz * 4 + tz + 2) & 31;
        int gy = (wy * 4 + ty + 2) & 31;
        int gx = (wx * 4 + tx + 2) & 31;
        const float* xp = x + ((((b * 32 + gz) * 32 + gy) * 32 + gx)) * 192;
        int g0 = q8 >> 1, j0 = (q8 & 1) * 4, lt = t & 15;
#pragma unroll
        for (int k = 0; k < 6; ++k) {
            float4 v = *(const float4*)(xp + q8 * 4 + k * 32);
            uint2 pk;
            pk.x = f2bf2(v.x, v.y);
            pk.y = f2bf2(v.z, v.w);
            *(uint2*)&smem[OFF_X + ((((k * 4 + g0) * 4 + tz) * 16 + lt) * 8) + j0] = pk;
        }
    }

    // hoist first phase-1 B fragment (global only, overlaps barrier drain)
    int nb = wv;
    float bias = bq[nb * 16 + l15];
    bf16x8 bfr[6];
    {
        const unsigned short* wp = WqT + (nb * 16 + l15) * 192 + g * 8;
#pragma unroll
        for (int kk = 0; kk < 6; ++kk) bfr[kk] = *(const bf16x8*)(wp + kk * 32);
    }
    __syncthreads();

    // ---------- phase 1: QKV = Xw(64x192) @ WqT^T + bq  (64x576) ----------
    {
        bf16x8 afr[4][6];          // A fragments cached: 4 m-blocks x 6 k-iters
#pragma unroll
        for (int m = 0; m < 4; ++m)
#pragma unroll
            for (int kk = 0; kk < 6; ++kk)
                afr[m][kk] = *(const bf16x8*)&smem[OFF_X + (((kk * 4 + g) * 4 + m) * 16 + l15) * 8];

        while (true) {
            int nbN = nb + 8;
            bool more = (nbN < 36);
            bf16x8 bfrN[6];
            float biasN = 0.f;
            if (more) {
                biasN = bq[nbN * 16 + l15];
                const unsigned short* wp = WqT + (nbN * 16 + l15) * 192 + g * 8;
#pragma unroll
                for (int kk = 0; kk < 6; ++kk) bfrN[kk] = *(const bf16x8*)(wp + kk * 32);
            }
            int colg = nb * 16 + l15;
            bool isV = (nb >= 24);
#pragma unroll
            for (int m = 0; m < 4; ++m) {
                f32x4 acc = {bias, bias, bias, bias};
#pragma unroll
                for (int kk = 0; kk < 6; ++kk) acc = MFMA16(afr[m][kk], bfr[kk], acc);
                int row0 = m * 16 + g * 4;
                unsigned int u01 = f2bf2(acc[0], acc[1]);
                unsigned int u23 = f2bf2(acc[2], acc[3]);
                if (!isV) {                       // Q/K -> sQK[t][col]
                    unsigned short* qk = &smem[OFF_QK + row0 * 392 + colg];
                    qk[0]    = (unsigned short)u01;
                    qk[392]  = (unsigned short)(u01 >> 16);
                    qk[784]  = (unsigned short)u23;
                    qk[1176] = (unsigned short)(u23 >> 16);
                } else {                          // V -> sVt[c][t], 4 contiguous t
                    uint2 pk; pk.x = u01; pk.y = u23;
                    *(uint2*)&smem[OFF_VT + (colg - 384) * 72 + row0] = pk;
                }
            }
            if (!more) break;
            nb = nbN;
            bias = biasN;
#pragma unroll
            for (int kk = 0; kk < 6; ++kk) bfr[kk] = bfrN[kk];
        }
    }
    __syncthreads();

    // ---------- phase 2: per (head, 16-row block) attention, software-pipelined ----------
    const bool sz = (wz == 7), sy = (wy == 7), sx = (wx == 7);
    const bool anym = sz | sy | sx;     // block-uniform
    {
        const int qy = l15 >> 2, qx = l15 & 3;
        const bool my = sy && ((g < 2) != (qy < 2));
        bool mxr[4];
#pragma unroll
        for (int r = 0; r < 4; ++r) mxr[r] = sx && ((r < 2) != (qx < 2));
        unsigned short* pb = &smem[OFF_P + wv * 1152];
        const int it0 = wv * 3;
        int h = it0 >> 2, mb = it0 & 3;

        // preload iteration 0 operands (bias table VMEM + q/k frags LDS)
        bf16x8 qf, kf[4];
        f32x4 bv[4];
        {
            const f32x4* tp = (const f32x4*)(tblB + ((h * 4 + mb) * 64 + lane) * 16);
#pragma unroll
            for (int f = 0; f < 4; ++f) bv[f] = tp[f];
            qf = *(const bf16x8*)&smem[OFF_QK + (mb * 16 + l15) * 392 + h * 32 + g * 8];
#pragma unroll
            for (int f = 0; f < 4; ++f)
                kf[f] = *(const bf16x8*)&smem[OFF_QK + (f * 16 + l15) * 392 + 192 + h * 32 + g * 8];
        }

#pragma unroll
        for (int ii = 0; ii < 3; ++ii) {
            // prefetch next iteration's operands (latency hides under this iter's tail)
            bf16x8 qfN, kfN[4];
            f32x4 bvN[4];
            if (ii < 2) {
                int itN = it0 + ii + 1;
                int hN = itN >> 2, mbN = itN & 3;
                const f32x4* tp = (const f32x4*)(tblB + ((hN * 4 + mbN) * 64 + lane) * 16);
#pragma unroll
                for (int f = 0; f < 4; ++f) bvN[f] = tp[f];
                qfN = *(const bf16x8*)&smem[OFF_QK + (mbN * 16 + l15) * 392 + hN * 32 + g * 8];
#pragma unroll
                for (int f = 0; f < 4; ++f)
                    kfN[f] = *(const bf16x8*)&smem[OFF_QK + (f * 16 + l15) * 392 + 192 + hN * 32 + g * 8];
            }
            // V fragments early: independent of the P round-trip below
            const int vtb = OFF_VT + (h * 32 + l15) * 72 + g * 8;
            bf16x8 v00 = *(const bf16x8*)&smem[vtb];
            bf16x8 v01 = *(const bf16x8*)&smem[vtb + 32];
            bf16x8 v10 = *(const bf16x8*)&smem[vtb + 16 * 72];
            bf16x8 v11 = *(const bf16x8*)&smem[vtb + 16 * 72 + 32];

            f32x4 s[4];
#pragma unroll
            for (int f = 0; f < 4; ++f) {
                f32x4 z = {0.f, 0.f, 0.f, 0.f};
                s[f] = MFMA16(qf, kf[f], z);
            }
            // bias + (uniform-branch) shift mask + exp2 (log2 domain)
            if (!anym) {
#pragma unroll
                for (int f = 0; f < 4; ++f)
#pragma unroll
                    for (int r = 0; r < 4; ++r)
                        s[f][r] = exp2f(s[f][r] + bv[f][r]);
            } else {
#pragma unroll
                for (int f = 0; f < 4; ++f) {
                    bool mzy = (sz && ((mb < 2) != (f < 2))) | my;
#pragma unroll
                    for (int r = 0; r < 4; ++r) {
                        float v = s[f][r] + bv[f][r];
                        v = (mzy | mxr[r]) ? -1e30f : v;
                        s[f][r] = exp2f(v);
                    }
                }
            }
            // row sums via DPP; P stays unnormalized
            float inv[4];
#pragma unroll
            for (int r = 0; r < 4; ++r) {
                float sm = (s[0][r] + s[1][r]) + (s[2][r] + s[3][r]);
                DPPADD(sm, 0xB1);    // quad_perm [1,0,3,2]
                DPPADD(sm, 0x4E);    // quad_perm [2,3,0,1]
                DPPADD(sm, 0x124);   // row_ror:4
                DPPADD(sm, 0x128);   // row_ror:8
                inv[r] = __builtin_amdgcn_rcpf(sm);
            }
            // P (C-layout) -> per-wave LDS -> A-frags (same wave, no barrier)
#pragma unroll
            for (int f = 0; f < 4; ++f) {
                unsigned int u01 = f2bf2(s[f][0], s[f][1]);
                unsigned int u23 = f2bf2(s[f][2], s[f][3]);
                unsigned short* pw = &pb[(g * 4) * 72 + f * 16 + l15];
                pw[0]   = (unsigned short)u01;
                pw[72]  = (unsigned short)(u01 >> 16);
                pw[144] = (unsigned short)u23;
                pw[216] = (unsigned short)(u23 >> 16);
            }
            bf16x8 pf0 = *(const bf16x8*)&pb[l15 * 72 + g * 8];
            bf16x8 pf1 = *(const bf16x8*)&pb[l15 * 72 + 32 + g * 8];
            // PV: O(16x32) = P(16x64) @ V(64x32), then normalize by inv[r]
            f32x4 o0 = {0.f, 0.f, 0.f, 0.f}, o1 = {0.f, 0.f, 0.f, 0.f};
            o0 = MFMA16(pf0, v00, o0);
            o1 = MFMA16(pf0, v10, o1);
            o0 = MFMA16(pf1, v01, o0);
            o1 = MFMA16(pf1, v11, o1);
#pragma unroll
            for (int r = 0; r < 4; ++r) { o0[r] *= inv[r]; o1[r] *= inv[r]; }
            unsigned int a0 = f2bf2(o0[0], o0[1]), a1 = f2bf2(o0[2], o0[3]);
            unsigned int c0 = f2bf2(o1[0], o1[1]), c1 = f2bf2(o1[2], o1[3]);
            unsigned short* ow = &smem[OFF_O + (mb * 16 + g * 4) * 208 + h * 32 + l15];
            ow[0]        = (unsigned short)a0;
            ow[208]      = (unsigned short)(a0 >> 16);
            ow[416]      = (unsigned short)a1;
            ow[624]      = (unsigned short)(a1 >> 16);
            ow[16]       = (unsigned short)c0;
            ow[16 + 208] = (unsigned short)(c0 >> 16);
            ow[16 + 416] = (unsigned short)c1;
            ow[16 + 624] = (unsigned short)(c1 >> 16);
            // rotate pipeline registers
            if (ii < 2) {
                int itN = it0 + ii + 1;
                h = itN >> 2; mb = itN & 3;
                qf = qfN;
#pragma unroll
                for (int f = 0; f < 4; ++f) { kf[f] = kfN[f]; bv[f] = bvN[f]; }
            }
        }
    }

    // hoist first phase-3 B fragment + bias (global only, overlaps barrier drain)
    const int mw = wv >> 2, nq = wv & 3;
    int col0 = nq * 16 + l15;
    float boc = bout[col0];
    bf16x8 bfr3[6];
    {
        const unsigned short* wp = WoT + col0 * 192 + g * 8;
#pragma unroll
        for (int kk = 0; kk < 6; ++kk) bfr3[kk] = *(const bf16x8*)(wp + kk * 32);
    }
    __syncthreads();

    // ---------- phase 3: out = O(64x192) @ WoT^T + b_out, scatter to global ----------
    {
        bf16x8 ofr[2][6];
#pragma unroll
        for (int mi = 0; mi < 2; ++mi)
#pragma unroll
            for (int kk = 0; kk < 6; ++kk)
                ofr[mi][kk] = *(const bf16x8*)&smem[OFF_O + ((mw * 2 + mi) * 16 + l15) * 208 + kk * 32 + g * 8];
#pragma unroll
        for (int nbi = 0; nbi < 3; ++nbi) {
            int col = (nq + nbi * 4) * 16 + l15;
            // prefetch next n-block's W fragments before computing this one
            float boN = 0.f;
            bf16x8 bfrN[6];
            if (nbi < 2) {
                int colN = (nq + (nbi + 1) * 4) * 16 + l15;
                boN = bout[colN];
                const unsigned short* wp = WoT + colN * 192 + g * 8;
#pragma unroll
                for (int kk = 0; kk < 6; ++kk) bfrN[kk] = *(const bf16x8*)(wp + kk * 32);
            }
#pragma unroll
            for (int mi = 0; mi < 2; ++mi) {
                f32x4 acc = {boc, boc, boc, boc};
#pragma unroll
                for (int kk = 0; kk < 6; ++kk) acc = MFMA16(ofr[mi][kk], bfr3[kk], acc);
                int m = mw * 2 + mi;                    // token t = m*16 + g*4 + r
                int gz = (wz * 4 + m + 2) & 31;         // roll(+2) folded in
                int gy = (wy * 4 + g + 2) & 31;
#pragma unroll
                for (int r = 0; r < 4; ++r) {
                    int gx = (wx * 4 + r + 2) & 31;
                    out[(((b * 32 + gz) * 32 + gy) * 32 + gx) * 192 + col] = acc[r];
                }
            }
            boc = boN;
#pragma unroll
            for (int kk = 0; kk < 6; ++kk) bfr3[kk] = bfrN[kk];
        }
    }
}

extern "C" void kernel_launch(void* const* d_in, const int* in_sizes, int n_in,
                              void* d_out, int out_size, void* d_ws, size_t ws_size,
                              hipStream_t stream) {
    const float* x    = (const float*)d_in[0];
    const float* Wqkv = (const float*)d_in[1];
    const float* bqkv = (const float*)d_in[2];
    const float* rel  = (const float*)d_in[3];
    const float* Wout = (const float*)d_in[4];
    const float* bout = (const float*)d_in[5];

    unsigned short* WqT = (unsigned short*)((char*)d_ws + WQT_OFF);
    unsigned short* WoT = (unsigned short*)((char*)d_ws + WOT_OFF);
    float*          bq  = (float*)((char*)d_ws + BQ_OFF);
    float*          tbl = (float*)((char*)d_ws + TBL_OFF);
    float*          out = (float*)d_out;

    prep_kernel<<<241, 256, 0, stream>>>(Wqkv, bqkv, Wout, rel, WqT, WoT, bq, tbl);
    wmsa_kernel<<<1024, 512, 0, stream>>>(x, tbl, bout, WqT, WoT, bq, out);
}